// Round 1
// baseline (49.252 us; speedup 1.0000x reference)
//
#include <hip/hip_runtime.h>

#define D_MODEL 2048
#define D4 (D_MODEL / 4)   // 512 float4 per row

// One wave (64 lanes) computes one row's 3 dot products over D=2048,
// then lanes 0..2 apply bias + the T-step diffusion recurrence and write.
// W (3 x 2048 f32 = 24 KB) is staged to LDS once per block.
__global__ __launch_bounds__(256) void diff_coord_kernel(
    const float* __restrict__ latent,
    const float* __restrict__ W,
    const float* __restrict__ b,
    const float* __restrict__ noise,
    const int*   __restrict__ tsteps,
    float*       __restrict__ out,
    int nrows)
{
    __shared__ float4 wlds[3][D4];   // 24 KB

    // Cooperative W stage: 3*512 = 1536 float4, 256 threads -> 6 each.
    const float4* W4 = reinterpret_cast<const float4*>(W);
    for (int i = threadIdx.x; i < 3 * D4; i += 256) {
        wlds[i / D4][i % D4] = W4[i];
    }
    __syncthreads();

    const int wid  = threadIdx.x >> 6;   // wave id in block: 0..3
    const int lane = threadIdx.x & 63;   // wave = 64 on CDNA
    const int T    = tsteps[0];

    for (int row = blockIdx.x * 4 + wid; row < nrows; row += gridDim.x * 4) {
        const float4* lat4 =
            reinterpret_cast<const float4*>(latent) + (size_t)row * D4;

        float a0 = 0.0f, a1 = 0.0f, a2 = 0.0f;
        #pragma unroll
        for (int k = 0; k < D4 / 64; ++k) {       // 8 iterations
            const int j = k * 64 + lane;          // coalesced: lane i -> 16B at 16*i
            const float4 x  = lat4[j];
            const float4 w0 = wlds[0][j];
            const float4 w1 = wlds[1][j];
            const float4 w2 = wlds[2][j];
            a0 += x.x * w0.x; a0 += x.y * w0.y; a0 += x.z * w0.z; a0 += x.w * w0.w;
            a1 += x.x * w1.x; a1 += x.y * w1.y; a1 += x.z * w1.z; a1 += x.w * w1.w;
            a2 += x.x * w2.x; a2 += x.y * w2.y; a2 += x.z * w2.z; a2 += x.w * w2.w;
        }

        // 64-lane butterfly reduction (all lanes end with the full sum).
        #pragma unroll
        for (int off = 32; off >= 1; off >>= 1) {
            a0 += __shfl_xor(a0, off);
            a1 += __shfl_xor(a1, off);
            a2 += __shfl_xor(a2, off);
        }

        if (lane < 3) {
            const float c = (lane == 0 ? a0 : (lane == 1 ? a1 : a2)) + b[lane];
            float x = noise[(size_t)row * 3 + lane];
            // x_{k+1} = alpha*x_k + (1-alpha)*c, alpha=(t+1)/T, t=T-1..0
            for (int t = T - 1; t >= 0; --t) {
                const float alpha = (float)(t + 1) / (float)T;
                x = alpha * x + (1.0f - alpha) * c;
            }
            out[(size_t)row * 3 + lane] = x;
        }
    }
}

extern "C" void kernel_launch(void* const* d_in, const int* in_sizes, int n_in,
                              void* d_out, int out_size, void* d_ws, size_t ws_size,
                              hipStream_t stream) {
    const float* latent = (const float*)d_in[0];
    const float* W      = (const float*)d_in[1];
    const float* b      = (const float*)d_in[2];
    const float* noise  = (const float*)d_in[3];
    const int*   tsteps = (const int*)d_in[4];
    float* out = (float*)d_out;

    const int nrows = in_sizes[0] / D_MODEL;   // B*S = 32768

    // Grid-stride: 2048 blocks x 4 waves = 8192 rows per sweep, 4 sweeps.
    // Keeps W staging to 2048 blocks while saturating all 256 CUs.
    diff_coord_kernel<<<2048, 256, 0, stream>>>(latent, W, b, noise, tsteps,
                                                out, nrows);
}